// Round 3
// baseline (152.484 us; speedup 1.0000x reference)
//
#include <hip/hip_runtime.h>

#define BB 8
#define CC 128
#define HH 112
#define WW 112
#define GG 4
#define CGr 32       // channels per group
#define KK2 9        // K*K
#define OCG 32       // out channels per group
#define TH 16
#define TW 16
#define HALO_H 18
#define HALO_W 18
#define NPIX (HALO_H * HALO_W)   // 324 pixels incl. halo
#define CSTR 36                  // channel stride (pad 32->36): keeps float4 16B-aligned,
                                 // start bank = (4*tx+8*ty)%32 -> 8 lanes per 4-bank quad (uniform)
#define NT 256

__global__ __launch_bounds__(NT, 3)
void invol_fused(const float* __restrict__ x,
                 const float* __restrict__ w_kg,
                 const float* __restrict__ b_kg,
                 const float* __restrict__ w_pw,
                 const float* __restrict__ b_pw,
                 float* __restrict__ out)
{
    // channel-contiguous: xs[pixel][channel] -> ds_read_b128 over 4 channels
    __shared__ float xs[NPIX][CSTR];   // 324*36*4 = 46,656 B -> 3 blocks/CU

    const int tile  = blockIdx.x;      // 49 tiles of 16x16
    const int tileh = tile / 7;
    const int tilew = tile - tileh * 7;
    const int g = blockIdx.y;
    const int b = blockIdx.z;
    const int h0 = tileh * TH;
    const int w0 = tilew * TW;
    const int tid = threadIdx.x;

    // ---- stage x tile (+1 halo), transposing to [pixel][c] ----
    {
        const float* xg = x + (size_t)(b * CC + g * CGr) * (HH * WW);
        for (int i = tid; i < CGr * NPIX; i += NT) {
            int c   = i / NPIX;
            int q   = i - c * NPIX;          // pixel index, col-fastest -> global coalesced
            int r   = q / HALO_W;
            int col = q - r * HALO_W;
            int gh = h0 - 1 + r;
            int gw = w0 - 1 + col;
            float v = 0.0f;
            if ((unsigned)gh < (unsigned)HH && (unsigned)gw < (unsigned)WW)
                v = xg[(size_t)c * (HH * WW) + gh * WW + gw];
            xs[q][c] = v;
        }
    }
    __syncthreads();

    const int tx = tid & 15;
    const int ty = tid >> 4;
    const int qbase = ty * HALO_W + tx;    // patch top-left pixel

    // wave-uniform weight bases -> scalar (s_load) path
    const float* wk = w_kg + (size_t)g * (KK2 * CGr * KK2);  // ((g*9+t)*32+c)*9+u
    const float* bk = b_kg + g * KK2;
    const float* wp = w_pw + (size_t)g * (OCG * CGr);        // (g*32+o)*32+c
    const float* bp = b_pw + g * OCG;

    // ---- pass 1: per-pixel dynamic kernel kv[9] ----
    float kv[KK2];
    #pragma unroll
    for (int t = 0; t < KK2; ++t) kv[t] = bk[t];

    #pragma unroll 1
    for (int c4 = 0; c4 < CGr / 4; ++c4) {     // 8 chunks of 4 channels
        float4 p[KK2];
        #pragma unroll
        for (int u = 0; u < KK2; ++u) {
            int q = qbase + (u / 3) * HALO_W + (u % 3);
            p[u] = *(const float4*)&xs[q][c4 * 4];
        }
        const float* pf = (const float*)p;     // pf[u*4+cc], compile-time indices only
        #pragma unroll
        for (int t = 0; t < KK2; ++t) {
            const float* wr = wk + (size_t)(t * CGr + c4 * 4) * KK2;  // 36 consecutive floats
            float a = kv[t];
            #pragma unroll
            for (int cc = 0; cc < 4; ++cc)
                #pragma unroll
                for (int u = 0; u < KK2; ++u)
                    a = fmaf(pf[u * 4 + cc], wr[cc * KK2 + u], a);
            kv[t] = a;
        }
    }

    // ---- pass 2: involution m[c] = sum_u patch * kv  (fully unrolled: m indices static) ----
    float m[CGr];
    #pragma unroll
    for (int c4 = 0; c4 < CGr / 4; ++c4) {
        float4 p[KK2];
        #pragma unroll
        for (int u = 0; u < KK2; ++u) {
            int q = qbase + (u / 3) * HALO_W + (u % 3);
            p[u] = *(const float4*)&xs[q][c4 * 4];
        }
        const float* pf = (const float*)p;
        #pragma unroll
        for (int cc = 0; cc < 4; ++cc) {
            float a = 0.0f;
            #pragma unroll
            for (int u = 0; u < KK2; ++u)
                a = fmaf(pf[u * 4 + cc], kv[u], a);
            m[c4 * 4 + cc] = a;
        }
    }

    // ---- pass 3: grouped 1x1 pointwise; weight rows contiguous -> s_load_dwordx8 ----
    const int gh = h0 + ty;
    const int gw = w0 + tx;
    float* og = out + ((size_t)(b * CC + g * OCG) * HH + gh) * WW + gw;
    #pragma unroll 1
    for (int o = 0; o < OCG; ++o) {
        const float* wr = wp + (size_t)o * CGr;   // 32 consecutive floats
        float a = bp[o];
        #pragma unroll
        for (int c = 0; c < CGr; ++c)
            a = fmaf(m[c], wr[c], a);
        og[(size_t)o * (HH * WW)] = a;
    }
}

extern "C" void kernel_launch(void* const* d_in, const int* in_sizes, int n_in,
                              void* d_out, int out_size, void* d_ws, size_t ws_size,
                              hipStream_t stream)
{
    const float* x    = (const float*)d_in[0];
    const float* w_kg = (const float*)d_in[1];
    const float* b_kg = (const float*)d_in[2];
    const float* w_pw = (const float*)d_in[3];
    const float* b_pw = (const float*)d_in[4];
    float* out = (float*)d_out;

    dim3 grid(49, GG, BB);
    dim3 block(NT);
    hipLaunchKernelGGL(invol_fused, grid, block, 0, stream,
                       x, w_kg, b_kg, w_pw, b_pw, out);
}

// Round 4
// 59.976 us; speedup vs baseline: 2.5424x; 2.5424x over previous
//
#include <hip/hip_runtime.h>
#include <hip/hip_bf16.h>

typedef __attribute__((ext_vector_type(8))) short short8;
typedef __attribute__((ext_vector_type(4))) float f32x4;
typedef __attribute__((ext_vector_type(4))) unsigned int u32x4;

#define GG 4
#define CC 128
#define HH 112
#define WW 112
#define TH 16
#define TW 16
#define HALO 18
#define NPIX (HALO * HALO)      // 324
#define XSTR 40                 // bf16 per pixel row: pad 32->40 (80B: 16B-aligned, 2-way banks)
#define NT 256
#define WK_ELEMS (4 * 9 * 16 * 32)   // 18432 bf16: wk_reord[g][u][t16][c32], taps 9..15 zero
#define WP_ELEMS (4 * 2 * 16 * 32)   // 4096  bf16: wp_reord[g][mt][o16][c32]

// ---- prologue: reorder weights into MFMA A-fragment layout (bf16) in d_ws ----
__global__ __launch_bounds__(256)
void reorder_weights(const float* __restrict__ w_kg, const float* __restrict__ w_pw,
                     unsigned short* __restrict__ ws)
{
    int idx = blockIdx.x * 256 + threadIdx.x;
    if (idx < WK_ELEMS) {
        int c = idx & 31, t = (idx >> 5) & 15, r = idx >> 9;
        int u = r % 9, g = r / 9;
        float v = (t < 9) ? w_kg[((g * 9 + t) * 32 + c) * 9 + u] : 0.0f;
        ws[idx] = __builtin_bit_cast(unsigned short, __float2bfloat16(v));
    } else if (idx < WK_ELEMS + WP_ELEMS) {
        int j = idx - WK_ELEMS;
        int c = j & 31, o = (j >> 5) & 15, mt = (j >> 9) & 1, g = j >> 10;
        float v = w_pw[(g * 32 + mt * 16 + o) * 32 + c];
        ws[idx] = __builtin_bit_cast(unsigned short, __float2bfloat16(v));
    }
}

__global__ __launch_bounds__(NT, 3)
void invol_mfma(const float* __restrict__ x,
                const float* __restrict__ b_kg,
                const float* __restrict__ b_pw,
                const unsigned short* __restrict__ ws,
                float* __restrict__ out)
{
    __shared__ unsigned short xs[NPIX * XSTR];   // 25,920 B  [pixel][channel] bf16
    __shared__ float kvl[4 * 16 * 12];           //  3,072 B  per-wave kv roundtrip

    const int tile  = blockIdx.x;                // 49 tiles of 16x16
    const int tileh = tile / 7;
    const int tilew = tile - tileh * 7;
    const int g = blockIdx.y;
    const int b = blockIdx.z;
    const int h0 = tileh * TH;
    const int w0 = tilew * TW;
    const int tid = threadIdx.x;

    // ---- stage x tile (+halo) as bf16, [pixel][channel] ----
    {
        const float* xg = x + (size_t)(b * CC + g * 32) * (HH * WW);
        for (int i = tid; i < 32 * NPIX; i += NT) {
            int c = i / NPIX;
            int q = i - c * NPIX;
            int r = q / HALO;
            int col = q - r * HALO;
            int gh = h0 - 1 + r;
            int gw = w0 - 1 + col;
            float v = 0.0f;
            if ((unsigned)gh < (unsigned)HH && (unsigned)gw < (unsigned)WW)
                v = xg[(size_t)c * (HH * WW) + gh * WW + gw];
            xs[q * XSTR + c] = __builtin_bit_cast(unsigned short, __float2bfloat16(v));
        }
    }
    __syncthreads();

    const int lane = tid & 63;
    const int wid  = tid >> 6;
    const int px   = lane & 15;     // MFMA col index (pixel) & A-row supplier index
    const int kb   = lane >> 4;     // k-chunk: this lane's 8 channels = 8*kb..8*kb+7

    // ---- A-fragments: kernel-gen weights (9 K-steps) + pointwise (2 M-tiles), loaded once ----
    short8 afrag[9];
    #pragma unroll
    for (int u = 0; u < 9; ++u)
        afrag[u] = *(const short8*)(ws + (((g * 9 + u) * 16 + px) * 32 + kb * 8));
    short8 wpfrag[2];
    #pragma unroll
    for (int mt = 0; mt < 2; ++mt)
        wpfrag[mt] = *(const short8*)(ws + WK_ELEMS + (((g * 2 + mt) * 16 + px) * 32 + kb * 8));

    // biases (clamped index for invalid tap rows; their kv is never consumed)
    const float* bk = b_kg + g * 9;
    const float* bp = b_pw + g * 32;
    float bkv[4];
    #pragma unroll
    for (int r = 0; r < 4; ++r) {
        int t = 4 * kb + r;
        bkv[r] = bk[t < 9 ? t : 0];
    }
    float bpv[8];
    #pragma unroll
    for (int mt = 0; mt < 2; ++mt)
        #pragma unroll
        for (int r = 0; r < 4; ++r)
            bpv[mt * 4 + r] = bp[mt * 16 + 4 * kb + r];

    float* kvp = &kvl[(wid * 16 + px) * 12];
    const size_t HW = (size_t)HH * WW;
    const size_t obase = ((size_t)(b * CC + g * 32) * HH + h0) * WW + w0 + px;

    // ---- 4 pixel-row chunks per wave (16 pixels each) ----
    #pragma unroll 1
    for (int r = 0; r < 4; ++r) {
        const int py = wid * 4 + r;

        // B-fragments: one ds_read_b128 per tap (8 channels of this lane's pixel)
        short8 bfrag[9];
        #pragma unroll
        for (int u = 0; u < 9; ++u) {
            int q = (py + u / 3) * HALO + (px + u % 3);
            bfrag[u] = *(const short8*)&xs[q * XSTR + kb * 8];
        }

        // stage 1: kv[16,16] = Wk * P  (K = 9 taps x 32 ch)
        f32x4 kv = {0.f, 0.f, 0.f, 0.f};
        #pragma unroll
        for (int u = 0; u < 9; ++u)
            kv = __builtin_amdgcn_mfma_f32_16x16x32_bf16(afrag[u], bfrag[u], kv, 0, 0, 0);

        // kv cross-lane roundtrip (+bias): lane holds taps 4*kb..4*kb+3 of pixel px
        if (kb < 2) {
            f32x4 kvb;
            #pragma unroll
            for (int i = 0; i < 4; ++i) kvb[i] = kv[i] + bkv[i];
            *(f32x4*)&kvp[4 * kb] = kvb;
        } else if (kb == 2) {
            kvp[8] = kv[0] + bkv[0];
        }
        // all lanes read the 9 taps of their pixel (broadcast across kb groups)
        f32x4 k03 = *(const f32x4*)&kvp[0];
        f32x4 k47 = *(const f32x4*)&kvp[4];
        float k8 = kvp[8];
        float kvv[9] = {k03.x, k03.y, k03.z, k03.w, k47.x, k47.y, k47.z, k47.w, k8};

        // stage 2: involution on VALU, reusing bfrag registers (no extra LDS reads)
        float m[8] = {0.f, 0.f, 0.f, 0.f, 0.f, 0.f, 0.f, 0.f};
        #pragma unroll
        for (int u = 0; u < 9; ++u) {
            u32x4 bu = __builtin_bit_cast(u32x4, bfrag[u]);
            #pragma unroll
            for (int w = 0; w < 4; ++w) {
                unsigned d = bu[w];
                float lo = __builtin_bit_cast(float, d << 16);
                float hi = __builtin_bit_cast(float, d & 0xffff0000u);
                m[2 * w]     = fmaf(lo, kvv[u], m[2 * w]);
                m[2 * w + 1] = fmaf(hi, kvv[u], m[2 * w + 1]);
            }
        }

        // stage 3: pointwise via MFMA; m already in B-fragment layout (k = 8*kb+j)
        unsigned pk[4];
        #pragma unroll
        for (int w = 0; w < 4; ++w) {
            unsigned slo = __builtin_bit_cast(unsigned short, __float2bfloat16(m[2 * w]));
            unsigned shi = __builtin_bit_cast(unsigned short, __float2bfloat16(m[2 * w + 1]));
            pk[w] = slo | (shi << 16);
        }
        short8 mfrag = __builtin_bit_cast(short8, (u32x4){pk[0], pk[1], pk[2], pk[3]});

        f32x4 zero = {0.f, 0.f, 0.f, 0.f};
        f32x4 o0 = __builtin_amdgcn_mfma_f32_16x16x32_bf16(wpfrag[0], mfrag, zero, 0, 0, 0);
        f32x4 o1 = __builtin_amdgcn_mfma_f32_16x16x32_bf16(wpfrag[1], mfrag, zero, 0, 0, 0);

        // store: lane writes (o = mt*16 + 4*kb + reg, pixel (py, px))
        #pragma unroll
        for (int reg = 0; reg < 4; ++reg) {
            int o = 4 * kb + reg;
            out[obase + (size_t)o * HW + (size_t)py * WW] = o0[reg] + bpv[reg];
            out[obase + (size_t)(o + 16) * HW + (size_t)py * WW] = o1[reg] + bpv[4 + reg];
        }
    }
}

extern "C" void kernel_launch(void* const* d_in, const int* in_sizes, int n_in,
                              void* d_out, int out_size, void* d_ws, size_t ws_size,
                              hipStream_t stream)
{
    const float* x    = (const float*)d_in[0];
    const float* w_kg = (const float*)d_in[1];
    const float* b_kg = (const float*)d_in[2];
    const float* w_pw = (const float*)d_in[3];
    const float* b_pw = (const float*)d_in[4];
    float* out = (float*)d_out;
    unsigned short* ws = (unsigned short*)d_ws;

    int pre_blocks = (WK_ELEMS + WP_ELEMS + 255) / 256;
    hipLaunchKernelGGL(reorder_weights, dim3(pre_blocks), dim3(256), 0, stream,
                       w_kg, w_pw, ws);

    dim3 grid(49, GG, 8);
    hipLaunchKernelGGL(invol_mfma, grid, dim3(NT), 0, stream,
                       x, b_kg, b_pw, ws, out);
}

// Round 6
// 54.948 us; speedup vs baseline: 2.7751x; 1.0915x over previous
//
#include <hip/hip_runtime.h>
#include <hip/hip_bf16.h>

typedef __attribute__((ext_vector_type(8))) short short8;
typedef __attribute__((ext_vector_type(4))) float f32x4;
typedef __attribute__((ext_vector_type(4))) unsigned int u32x4;

#define GG 4
#define CC 128
#define HH 112
#define WW 112
#define HWSZ (HH * WW)
#define TH 16
#define TW 16
#define HALO 18
#define NPIX (HALO * HALO)      // 324
#define XSTR 40                 // bf16 per pixel row: pad 32->40 (80B: 16B-aligned b128 reads)
#define NT 256
#define WK_ELEMS (4 * 9 * 16 * 32)   // wk_reord[g][u][t16][c32], taps 9..15 zero
#define WP_ELEMS (4 * 2 * 16 * 32)   // wp_reord[g][mt][o16][c32]

// ---- prologue: reorder weights into MFMA A-fragment layout (bf16) in d_ws ----
__global__ __launch_bounds__(256)
void reorder_weights(const float* __restrict__ w_kg, const float* __restrict__ w_pw,
                     unsigned short* __restrict__ ws)
{
    int idx = blockIdx.x * 256 + threadIdx.x;
    if (idx < WK_ELEMS) {
        int c = idx & 31, t = (idx >> 5) & 15, r = idx >> 9;
        int u = r % 9, g = r / 9;
        float v = (t < 9) ? w_kg[((g * 9 + t) * 32 + c) * 9 + u] : 0.0f;
        ws[idx] = __builtin_bit_cast(unsigned short, __float2bfloat16(v));
    } else if (idx < WK_ELEMS + WP_ELEMS) {
        int j = idx - WK_ELEMS;
        int c = j & 31, o = (j >> 5) & 15, mt = (j >> 9) & 1, g = j >> 10;
        float v = w_pw[(g * 32 + mt * 16 + o) * 32 + c];
        ws[idx] = __builtin_bit_cast(unsigned short, __float2bfloat16(v));
    }
}

__global__ __launch_bounds__(NT, 3)
void invol_mfma(const float* __restrict__ x,
                const float* __restrict__ b_kg,
                const float* __restrict__ b_pw,
                const unsigned short* __restrict__ ws,
                float* __restrict__ out)
{
    __shared__ unsigned short xs[NPIX * XSTR];   // 25,920 B  [pixel][channel] bf16
    __shared__ float kvl[4 * 16 * 12];           //  3,072 B  per-wave kv roundtrip

    const int tile  = blockIdx.x;                // 49 tiles of 16x16
    const int tileh = tile / 7;
    const int tilew = tile - tileh * 7;
    const int g = blockIdx.y;
    const int b = blockIdx.z;
    const int h0 = tileh * TH;
    const int w0 = tilew * TW;
    const int tid = threadIdx.x;

    // ---- staging v2': task = (channel-pair, halo-row); batched loads,
    //      type-correct ushort stores (unsigned-int stores into a ushort
    //      array are TBAA-dead vs short-typed readers -> DSE hazard) ----
    {
        const float* xg = x + (size_t)(b * CC + g * 32) * HWSZ;
        #pragma unroll 1
        for (int pair = tid; pair < 16 * HALO; pair += NT) {   // 288 tasks
            const int c2 = pair & 15;            // channel pair: channels 2c2, 2c2+1
            const int r  = pair >> 4;            // halo row 0..17
            const int gh = h0 - 1 + r;
            const bool rowok = (unsigned)gh < (unsigned)HH;
            const float msk = rowok ? 1.0f : 0.0f;
            const float* row0 = xg + (size_t)(2 * c2) * HWSZ + (size_t)(rowok ? gh : 0) * WW;
            const float* row1 = row0 + HWSZ;

            float4 i0[4], i1[4];                 // interior 16 px, aligned dwordx4
            #pragma unroll
            for (int j = 0; j < 4; ++j) {
                i0[j] = *(const float4*)(row0 + w0 + 4 * j);
                i1[j] = *(const float4*)(row1 + w0 + 4 * j);
            }
            float hl0 = 0.f, hl1 = 0.f, hr0 = 0.f, hr1 = 0.f;
            if (w0 > 0)       { hl0 = row0[w0 - 1];  hl1 = row1[w0 - 1]; }
            if (w0 + TW < WW) { hr0 = row0[w0 + TW]; hr1 = row1[w0 + TW]; }

            float v0[18], v1[18];
            v0[0] = hl0;  v1[0] = hl1;
            v0[17] = hr0; v1[17] = hr1;
            #pragma unroll
            for (int j = 0; j < 4; ++j) {
                v0[1 + 4 * j] = i0[j].x; v0[2 + 4 * j] = i0[j].y;
                v0[3 + 4 * j] = i0[j].z; v0[4 + 4 * j] = i0[j].w;
                v1[1 + 4 * j] = i1[j].x; v1[2 + 4 * j] = i1[j].y;
                v1[3 + 4 * j] = i1[j].z; v1[4 + 4 * j] = i1[j].w;
            }
            unsigned short* dst = &xs[(r * HALO) * XSTR + 2 * c2];
            #pragma unroll
            for (int col = 0; col < 18; ++col) {
                dst[col * XSTR]     = __builtin_bit_cast(unsigned short, __float2bfloat16(v0[col] * msk));
                dst[col * XSTR + 1] = __builtin_bit_cast(unsigned short, __float2bfloat16(v1[col] * msk));
            }
        }
    }
    __syncthreads();

    const int lane = tid & 63;
    const int wid  = tid >> 6;
    const int px   = lane & 15;     // MFMA col (pixel) & A-row index
    const int kb   = lane >> 4;     // k-chunk: 8 channels 8kb..8kb+7

    // A-fragments (loaded once; wave-uniform bases + lane offsets)
    short8 afrag[9];
    #pragma unroll
    for (int u = 0; u < 9; ++u)
        afrag[u] = *(const short8*)(ws + (((g * 9 + u) * 16 + px) * 32 + kb * 8));
    short8 wpfrag[2];
    #pragma unroll
    for (int mt = 0; mt < 2; ++mt)
        wpfrag[mt] = *(const short8*)(ws + WK_ELEMS + (((g * 2 + mt) * 16 + px) * 32 + kb * 8));

    const float* bk = b_kg + g * 9;
    const float* bp = b_pw + g * 32;
    float bkv[4];
    #pragma unroll
    for (int e = 0; e < 4; ++e) {
        int t = 4 * kb + e;
        bkv[e] = bk[t < 9 ? t : 0];     // clamped; invalid taps never consumed
    }
    float bpv[8];
    #pragma unroll
    for (int mt = 0; mt < 2; ++mt)
        #pragma unroll
        for (int e = 0; e < 4; ++e)
            bpv[mt * 4 + e] = bp[mt * 16 + 4 * kb + e];

    float* kvp = &kvl[(wid * 16 + px) * 12];
    const size_t obase = ((size_t)(b * CC + g * 32) * HH + h0) * WW + w0 + px;

    #pragma unroll 1
    for (int r = 0; r < 4; ++r) {
        const int py = wid * 4 + r;

        // B-fragments: one ds_read_b128 per tap
        short8 bfrag[9];
        #pragma unroll
        for (int u = 0; u < 9; ++u) {
            int q = (py + u / 3) * HALO + (px + u % 3);
            bfrag[u] = *(const short8*)&xs[q * XSTR + kb * 8];
        }

        // stage 1: kv = Wk * P  (K = 9 taps x 32 ch)
        f32x4 kv = {0.f, 0.f, 0.f, 0.f};
        #pragma unroll
        for (int u = 0; u < 9; ++u)
            kv = __builtin_amdgcn_mfma_f32_16x16x32_bf16(afrag[u], bfrag[u], kv, 0, 0, 0);

        // kv cross-lane roundtrip (+bias): lane holds taps 4*kb..4*kb+3 of pixel px
        if (kb < 2) {
            f32x4 kvb;
            #pragma unroll
            for (int i = 0; i < 4; ++i) kvb[i] = kv[i] + bkv[i];
            *(f32x4*)&kvp[4 * kb] = kvb;
        } else if (kb == 2) {
            kvp[8] = kv[0] + bkv[0];
        }
        f32x4 k03 = *(const f32x4*)&kvp[0];
        f32x4 k47 = *(const f32x4*)&kvp[4];
        float k8 = kvp[8];
        float kvv[9] = {k03.x, k03.y, k03.z, k03.w, k47.x, k47.y, k47.z, k47.w, k8};

        // stage 2: involution on VALU, reusing bfrag registers
        float m[8] = {0.f, 0.f, 0.f, 0.f, 0.f, 0.f, 0.f, 0.f};
        #pragma unroll
        for (int u = 0; u < 9; ++u) {
            u32x4 bu = __builtin_bit_cast(u32x4, bfrag[u]);
            #pragma unroll
            for (int w = 0; w < 4; ++w) {
                unsigned d = bu[w];
                float lo = __builtin_bit_cast(float, d << 16);
                float hi = __builtin_bit_cast(float, d & 0xffff0000u);
                m[2 * w]     = fmaf(lo, kvv[u], m[2 * w]);
                m[2 * w + 1] = fmaf(hi, kvv[u], m[2 * w + 1]);
            }
        }

        // stage 3: pointwise via MFMA; m already in B-fragment order (k = 8kb+j)
        unsigned pk[4];
        #pragma unroll
        for (int w = 0; w < 4; ++w) {
            unsigned slo = __builtin_bit_cast(unsigned short, __float2bfloat16(m[2 * w]));
            unsigned shi = __builtin_bit_cast(unsigned short, __float2bfloat16(m[2 * w + 1]));
            pk[w] = slo | (shi << 16);
        }
        short8 mfrag = __builtin_bit_cast(short8, (u32x4){pk[0], pk[1], pk[2], pk[3]});

        f32x4 zero = {0.f, 0.f, 0.f, 0.f};
        f32x4 o0 = __builtin_amdgcn_mfma_f32_16x16x32_bf16(wpfrag[0], mfrag, zero, 0, 0, 0);
        f32x4 o1 = __builtin_amdgcn_mfma_f32_16x16x32_bf16(wpfrag[1], mfrag, zero, 0, 0, 0);

        #pragma unroll
        for (int e = 0; e < 4; ++e) {
            int o = 4 * kb + e;
            out[obase + (size_t)o * HWSZ + (size_t)py * WW] = o0[e] + bpv[e];
            out[obase + (size_t)(o + 16) * HWSZ + (size_t)py * WW] = o1[e] + bpv[4 + e];
        }
    }
}

extern "C" void kernel_launch(void* const* d_in, const int* in_sizes, int n_in,
                              void* d_out, int out_size, void* d_ws, size_t ws_size,
                              hipStream_t stream)
{
    const float* x    = (const float*)d_in[0];
    const float* w_kg = (const float*)d_in[1];
    const float* b_kg = (const float*)d_in[2];
    const float* w_pw = (const float*)d_in[3];
    const float* b_pw = (const float*)d_in[4];
    float* out = (float*)d_out;
    unsigned short* ws = (unsigned short*)d_ws;

    int pre_blocks = (WK_ELEMS + WP_ELEMS + 255) / 256;
    hipLaunchKernelGGL(reorder_weights, dim3(pre_blocks), dim3(256), 0, stream,
                       w_kg, w_pw, ws);

    dim3 grid(49, GG, 8);
    hipLaunchKernelGGL(invol_mfma, grid, dim3(NT), 0, stream,
                       x, b_kg, b_pw, ws, out);
}

// Round 7
// 50.268 us; speedup vs baseline: 3.0334x; 1.0931x over previous
//
#include <hip/hip_runtime.h>
#include <hip/hip_bf16.h>

typedef __attribute__((ext_vector_type(8))) short short8;
typedef __attribute__((ext_vector_type(4))) float f32x4;
typedef __attribute__((ext_vector_type(4))) unsigned int u32x4;

#define GG 4
#define CC 128
#define HH 112
#define WW 112
#define HWSZ (HH * WW)
#define TH 16
#define TW 16
#define HALO 18
#define NPIX (HALO * HALO)      // 324
#define XSTR 40                 // bf16 per pixel row: pad 32->40 (80B: 16B-aligned b128 reads)
#define NT 256
#define WK_ELEMS (4 * 9 * 16 * 32)   // wk_reord[g][u][t16][c32], taps 9..15 zero
#define WP_ELEMS (4 * 2 * 16 * 32)   // wp_reord[g][mt][o16][c32]

// ---- prologue: reorder weights into MFMA A-fragment layout (bf16) in d_ws ----
__global__ __launch_bounds__(256)
void reorder_weights(const float* __restrict__ w_kg, const float* __restrict__ w_pw,
                     unsigned short* __restrict__ ws)
{
    int idx = blockIdx.x * 256 + threadIdx.x;
    if (idx < WK_ELEMS) {
        int c = idx & 31, t = (idx >> 5) & 15, r = idx >> 9;
        int u = r % 9, g = r / 9;
        float v = (t < 9) ? w_kg[((g * 9 + t) * 32 + c) * 9 + u] : 0.0f;
        ws[idx] = __builtin_bit_cast(unsigned short, __float2bfloat16(v));
    } else if (idx < WK_ELEMS + WP_ELEMS) {
        int j = idx - WK_ELEMS;
        int c = j & 31, o = (j >> 5) & 15, mt = (j >> 9) & 1, g = j >> 10;
        float v = w_pw[(g * 32 + mt * 16 + o) * 32 + c];
        ws[idx] = __builtin_bit_cast(unsigned short, __float2bfloat16(v));
    }
}

__global__ __launch_bounds__(NT, 4)
void invol_mfma(const float* __restrict__ x,
                const float* __restrict__ b_kg,
                const float* __restrict__ b_pw,
                const unsigned short* __restrict__ ws,
                float* __restrict__ out)
{
    __shared__ unsigned short xs[NPIX * XSTR];   // 25,920 B  [pixel][channel] bf16
    __shared__ float kvl[4 * 16 * 12];           //  3,072 B  per-wave kv roundtrip

    const int tile  = blockIdx.x;                // 49 tiles of 16x16
    const int tileh = tile / 7;
    const int tilew = tile - tileh * 7;
    const int g = blockIdx.y;
    const int b = blockIdx.z;
    const int h0 = tileh * TH;
    const int w0 = tilew * TW;
    const int tid = threadIdx.x;

    // ---- staging v3: coalesced (c-major, pixel-fastest), balanced 41 items/thread,
    //      3 unrolled batches: issue all loads -> one wait -> cvt+LDS write ----
    {
        const float* xg = x + (size_t)(b * CC + g * 32) * HWSZ;
        int c = 0, q = tid;                      // item i = tid + 256*itg; c=i/324, q=i%324
        #pragma unroll
        for (int batch = 0; batch < 3; ++batch) {
            const int bn = (batch == 2) ? 13 : 14;
            float v[14];
            int pki[14];
            #pragma unroll
            for (int it = 0; it < bn; ++it) {
                const int itg = batch * 14 + it;
                const bool valid = (itg < 40) || (tid < 128);   // 10368 items total
                int r   = (q * 57) >> 10;        // q/18 for q<324
                int col = q - 18 * r;
                int gh = h0 - 1 + r;
                int gw = w0 - 1 + col;
                bool ok = valid && ((unsigned)gh < (unsigned)HH) && ((unsigned)gw < (unsigned)WW);
                int ghc = min(max(gh, 0), HH - 1);
                int gwc = min(max(gw, 0), WW - 1);
                int cc  = min(c, 31);            // invalid-item clamp (stays in-bounds)
                float t = xg[(size_t)cc * HWSZ + ghc * WW + gwc];
                v[it]   = ok ? t : 0.0f;
                pki[it] = q * XSTR + c;          // c==32 lands in dead pad slot (never read)
                q += 256; if (q >= NPIX) { q -= NPIX; ++c; }
            }
            #pragma unroll
            for (int it = 0; it < bn; ++it)
                xs[pki[it]] = __builtin_bit_cast(unsigned short, __float2bfloat16(v[it]));
        }
    }
    __syncthreads();

    const int lane = tid & 63;
    const int wid  = tid >> 6;
    const int px   = lane & 15;     // MFMA col (pixel) & A-row index
    const int kb   = lane >> 4;     // k-chunk: 8 channels 8kb..8kb+7

    // A-fragments (loaded once; wave-uniform bases + lane offsets)
    short8 afrag[9];
    #pragma unroll
    for (int u = 0; u < 9; ++u)
        afrag[u] = *(const short8*)(ws + (((g * 9 + u) * 16 + px) * 32 + kb * 8));
    short8 wpfrag[2];
    #pragma unroll
    for (int mt = 0; mt < 2; ++mt)
        wpfrag[mt] = *(const short8*)(ws + WK_ELEMS + (((g * 2 + mt) * 16 + px) * 32 + kb * 8));

    const float* bk = b_kg + g * 9;
    const float* bp = b_pw + g * 32;
    float bkv[4];
    #pragma unroll
    for (int e = 0; e < 4; ++e) {
        int t = 4 * kb + e;
        bkv[e] = bk[t < 9 ? t : 0];     // clamped; invalid taps never consumed
    }
    float bpv[8];
    #pragma unroll
    for (int mt = 0; mt < 2; ++mt)
        #pragma unroll
        for (int e = 0; e < 4; ++e)
            bpv[mt * 4 + e] = bp[mt * 16 + 4 * kb + e];

    float* kvp = &kvl[(wid * 16 + px) * 12];
    const size_t obase = ((size_t)(b * CC + g * 32) * HH + h0) * WW + w0 + px;

    #pragma unroll 1
    for (int r = 0; r < 4; ++r) {
        const int py = wid * 4 + r;

        // B-fragments: one ds_read_b128 per tap
        short8 bfrag[9];
        #pragma unroll
        for (int u = 0; u < 9; ++u) {
            int q = (py + u / 3) * HALO + (px + u % 3);
            bfrag[u] = *(const short8*)&xs[q * XSTR + kb * 8];
        }

        // stage 1: kv = Wk * P  (K = 9 taps x 32 ch)
        f32x4 kv = {0.f, 0.f, 0.f, 0.f};
        #pragma unroll
        for (int u = 0; u < 9; ++u)
            kv = __builtin_amdgcn_mfma_f32_16x16x32_bf16(afrag[u], bfrag[u], kv, 0, 0, 0);

        // kv cross-lane roundtrip (+bias): lane holds taps 4*kb..4*kb+3 of pixel px
        if (kb < 2) {
            f32x4 kvb;
            #pragma unroll
            for (int i = 0; i < 4; ++i) kvb[i] = kv[i] + bkv[i];
            *(f32x4*)&kvp[4 * kb] = kvb;
        } else if (kb == 2) {
            kvp[8] = kv[0] + bkv[0];
        }
        f32x4 k03 = *(const f32x4*)&kvp[0];
        f32x4 k47 = *(const f32x4*)&kvp[4];
        float k8 = kvp[8];
        float kvv[9] = {k03.x, k03.y, k03.z, k03.w, k47.x, k47.y, k47.z, k47.w, k8};

        // stage 2: involution on VALU, reusing bfrag registers
        float m[8] = {0.f, 0.f, 0.f, 0.f, 0.f, 0.f, 0.f, 0.f};
        #pragma unroll
        for (int u = 0; u < 9; ++u) {
            u32x4 bu = __builtin_bit_cast(u32x4, bfrag[u]);
            #pragma unroll
            for (int w = 0; w < 4; ++w) {
                unsigned d = bu[w];
                float lo = __builtin_bit_cast(float, d << 16);
                float hi = __builtin_bit_cast(float, d & 0xffff0000u);
                m[2 * w]     = fmaf(lo, kvv[u], m[2 * w]);
                m[2 * w + 1] = fmaf(hi, kvv[u], m[2 * w + 1]);
            }
        }

        // stage 3: pointwise via MFMA; m already in B-fragment order (k = 8kb+j)
        unsigned pk[4];
        #pragma unroll
        for (int w = 0; w < 4; ++w) {
            unsigned slo = __builtin_bit_cast(unsigned short, __float2bfloat16(m[2 * w]));
            unsigned shi = __builtin_bit_cast(unsigned short, __float2bfloat16(m[2 * w + 1]));
            pk[w] = slo | (shi << 16);
        }
        short8 mfrag = __builtin_bit_cast(short8, (u32x4){pk[0], pk[1], pk[2], pk[3]});

        f32x4 zero = {0.f, 0.f, 0.f, 0.f};
        f32x4 o0 = __builtin_amdgcn_mfma_f32_16x16x32_bf16(wpfrag[0], mfrag, zero, 0, 0, 0);
        f32x4 o1 = __builtin_amdgcn_mfma_f32_16x16x32_bf16(wpfrag[1], mfrag, zero, 0, 0, 0);

        #pragma unroll
        for (int e = 0; e < 4; ++e) {
            int o = 4 * kb + e;
            out[obase + (size_t)o * HWSZ + (size_t)py * WW] = o0[e] + bpv[e];
            out[obase + (size_t)(o + 16) * HWSZ + (size_t)py * WW] = o1[e] + bpv[4 + e];
        }
    }
}

extern "C" void kernel_launch(void* const* d_in, const int* in_sizes, int n_in,
                              void* d_out, int out_size, void* d_ws, size_t ws_size,
                              hipStream_t stream)
{
    const float* x    = (const float*)d_in[0];
    const float* w_kg = (const float*)d_in[1];
    const float* b_kg = (const float*)d_in[2];
    const float* w_pw = (const float*)d_in[3];
    const float* b_pw = (const float*)d_in[4];
    float* out = (float*)d_out;
    unsigned short* ws = (unsigned short*)d_ws;

    int pre_blocks = (WK_ELEMS + WP_ELEMS + 255) / 256;
    hipLaunchKernelGGL(reorder_weights, dim3(pre_blocks), dim3(256), 0, stream,
                       w_kg, w_pw, ws);

    dim3 grid(49, GG, 8);
    hipLaunchKernelGGL(invol_mfma, grid, dim3(NT), 0, stream,
                       x, b_kg, b_pw, ws, out);
}

// Round 8
// 42.718 us; speedup vs baseline: 3.5696x; 1.1768x over previous
//
#include <hip/hip_runtime.h>
#include <hip/hip_bf16.h>

typedef __attribute__((ext_vector_type(8))) short short8;
typedef __attribute__((ext_vector_type(4))) float f32x4;
typedef __attribute__((ext_vector_type(4))) unsigned int u32x4;

#define GG 4
#define CC 128
#define HH 112
#define WW 112
#define HWSZ (HH * WW)
#define TH 16
#define TW 16
#define HALO 18
#define NPIX (HALO * HALO)      // 324
#define XSTR 40                 // bf16 per pixel row in LDS: pad 32->40 (80B; b128 reads conflict-free)
#define NT 256
#define WK_ELEMS (4 * 9 * 16 * 32)   // wk_reord[g][u][t16][c32], taps 9..15 zero
#define WP_ELEMS (4 * 2 * 16 * 32)   // wp_reord[g][mt][o16][c32]
#define XT_OFF 32768                 // ushort offset of x_t in ws (weights live in [0, 32768))
#define XT_ELEMS (8 * 4 * HWSZ * 32) // 12,845,056 ushorts
#define WS_NEED ((size_t)(XT_OFF + XT_ELEMS) * 2)

// ---- prologue: reorder weights into MFMA A-fragment layout (bf16) at ws[0..] ----
__global__ __launch_bounds__(256)
void reorder_weights(const float* __restrict__ w_kg, const float* __restrict__ w_pw,
                     unsigned short* __restrict__ ws)
{
    int idx = blockIdx.x * 256 + threadIdx.x;
    if (idx < WK_ELEMS) {
        int c = idx & 31, t = (idx >> 5) & 15, r = idx >> 9;
        int u = r % 9, g = r / 9;
        float v = (t < 9) ? w_kg[((g * 9 + t) * 32 + c) * 9 + u] : 0.0f;
        ws[idx] = __builtin_bit_cast(unsigned short, __float2bfloat16(v));
    } else if (idx < WK_ELEMS + WP_ELEMS) {
        int j = idx - WK_ELEMS;
        int c = j & 31, o = (j >> 5) & 15, mt = (j >> 9) & 1, g = j >> 10;
        float v = w_pw[(g * 32 + mt * 16 + o) * 32 + c];
        ws[idx] = __builtin_bit_cast(unsigned short, __float2bfloat16(v));
    }
}

// ---- transpose x -> x_t[b][g][pixel][c32] bf16 (channel-fastest) ----
__global__ __launch_bounds__(256, 4)
void transpose_x(const float* __restrict__ x, unsigned short* __restrict__ xt)
{
    __shared__ unsigned short xsT[32 * 452];     // [c][p448] pad 448->452; 28,928 B
    const int hc = blockIdx.x;                   // 28 chunks of 4 rows
    const int g = blockIdx.y, b = blockIdx.z;
    const int tid = threadIdx.x;
    const float* xg = x + (size_t)(b * CC + g * 32) * HWSZ + hc * 4 * WW;

    // phase 1: coalesced float4 reads (c-major, pixel-fastest), cvt, LDS write
    #pragma unroll
    for (int k = 0; k < 14; ++k) {               // 3584 tasks = 32c x 112 p4-groups
        int t = tid + 256 * k;
        int c = (t * 37450) >> 22;               // t/112, exact for t<3584
        int p4 = t - c * 112;
        float4 v = *(const float4*)(xg + (size_t)c * HWSZ + 4 * p4);
        int base = c * 452 + 4 * p4;
        xsT[base + 0] = __builtin_bit_cast(unsigned short, __float2bfloat16(v.x));
        xsT[base + 1] = __builtin_bit_cast(unsigned short, __float2bfloat16(v.y));
        xsT[base + 2] = __builtin_bit_cast(unsigned short, __float2bfloat16(v.z));
        xsT[base + 3] = __builtin_bit_cast(unsigned short, __float2bfloat16(v.w));
    }
    __syncthreads();

    // phase 2: gather 8 channels/pixel-chunk, write contiguous 16B (fully coalesced)
    unsigned short* xto = xt + ((size_t)(b * GG + g) * HWSZ + (size_t)hc * 448) * 32;
    #pragma unroll
    for (int k = 0; k < 7; ++k) {                // 1792 tasks = 448 px x 4 kb-chunks
        int t = tid + 256 * k;
        int p = t >> 2, kb = t & 3;
        unsigned r[4];
        #pragma unroll
        for (int j = 0; j < 4; ++j) {
            unsigned lo = xsT[(8 * kb + 2 * j) * 452 + p];
            unsigned hi = xsT[(8 * kb + 2 * j + 1) * 452 + p];
            r[j] = lo | (hi << 16);
        }
        *(u32x4*)(xto + (size_t)t * 8) = (u32x4){r[0], r[1], r[2], r[3]};
    }
}

// ---- shared compute body (identical in fast/fallback kernels) ----
__device__ __forceinline__ void compute_tile(
    const unsigned short* __restrict__ wsw, const float* __restrict__ b_kg,
    const float* __restrict__ b_pw, float* __restrict__ out,
    unsigned short* xs, float* kvl,
    int g, int b, int h0, int w0, int tid)
{
    const int lane = tid & 63;
    const int wid  = tid >> 6;
    const int px   = lane & 15;
    const int kb   = lane >> 4;

    short8 afrag[9];
    #pragma unroll
    for (int u = 0; u < 9; ++u)
        afrag[u] = *(const short8*)(wsw + (((g * 9 + u) * 16 + px) * 32 + kb * 8));
    short8 wpfrag[2];
    #pragma unroll
    for (int mt = 0; mt < 2; ++mt)
        wpfrag[mt] = *(const short8*)(wsw + WK_ELEMS + (((g * 2 + mt) * 16 + px) * 32 + kb * 8));

    const float* bk = b_kg + g * 9;
    const float* bp = b_pw + g * 32;
    float bkv[4];
    #pragma unroll
    for (int e = 0; e < 4; ++e) {
        int t = 4 * kb + e;
        bkv[e] = bk[t < 9 ? t : 0];
    }
    float bpv[8];
    #pragma unroll
    for (int mt = 0; mt < 2; ++mt)
        #pragma unroll
        for (int e = 0; e < 4; ++e)
            bpv[mt * 4 + e] = bp[mt * 16 + 4 * kb + e];

    float* kvp = &kvl[(wid * 16 + px) * 12];
    const size_t obase = ((size_t)(b * CC + g * 32) * HH + h0) * WW + w0 + px;

    #pragma unroll 1
    for (int r = 0; r < 4; ++r) {
        const int py = wid * 4 + r;

        short8 bfrag[9];
        #pragma unroll
        for (int u = 0; u < 9; ++u) {
            int q = (py + u / 3) * HALO + (px + u % 3);
            bfrag[u] = *(const short8*)&xs[q * XSTR + kb * 8];
        }

        f32x4 kv = {0.f, 0.f, 0.f, 0.f};
        #pragma unroll
        for (int u = 0; u < 9; ++u)
            kv = __builtin_amdgcn_mfma_f32_16x16x32_bf16(afrag[u], bfrag[u], kv, 0, 0, 0);

        if (kb < 2) {
            f32x4 kvb;
            #pragma unroll
            for (int i = 0; i < 4; ++i) kvb[i] = kv[i] + bkv[i];
            *(f32x4*)&kvp[4 * kb] = kvb;
        } else if (kb == 2) {
            kvp[8] = kv[0] + bkv[0];
        }
        f32x4 k03 = *(const f32x4*)&kvp[0];
        f32x4 k47 = *(const f32x4*)&kvp[4];
        float k8 = kvp[8];
        float kvv[9] = {k03.x, k03.y, k03.z, k03.w, k47.x, k47.y, k47.z, k47.w, k8};

        float m[8] = {0.f, 0.f, 0.f, 0.f, 0.f, 0.f, 0.f, 0.f};
        #pragma unroll
        for (int u = 0; u < 9; ++u) {
            u32x4 bu = __builtin_bit_cast(u32x4, bfrag[u]);
            #pragma unroll
            for (int w = 0; w < 4; ++w) {
                unsigned d = bu[w];
                float lo = __builtin_bit_cast(float, d << 16);
                float hi = __builtin_bit_cast(float, d & 0xffff0000u);
                m[2 * w]     = fmaf(lo, kvv[u], m[2 * w]);
                m[2 * w + 1] = fmaf(hi, kvv[u], m[2 * w + 1]);
            }
        }

        unsigned pk[4];
        #pragma unroll
        for (int w = 0; w < 4; ++w) {
            unsigned slo = __builtin_bit_cast(unsigned short, __float2bfloat16(m[2 * w]));
            unsigned shi = __builtin_bit_cast(unsigned short, __float2bfloat16(m[2 * w + 1]));
            pk[w] = slo | (shi << 16);
        }
        short8 mfrag = __builtin_bit_cast(short8, (u32x4){pk[0], pk[1], pk[2], pk[3]});

        f32x4 zero = {0.f, 0.f, 0.f, 0.f};
        f32x4 o0 = __builtin_amdgcn_mfma_f32_16x16x32_bf16(wpfrag[0], mfrag, zero, 0, 0, 0);
        f32x4 o1 = __builtin_amdgcn_mfma_f32_16x16x32_bf16(wpfrag[1], mfrag, zero, 0, 0, 0);

        #pragma unroll
        for (int e = 0; e < 4; ++e) {
            int o = 4 * kb + e;
            out[obase + (size_t)o * HWSZ + (size_t)py * WW] = o0[e] + bpv[e];
            out[obase + (size_t)(o + 16) * HWSZ + (size_t)py * WW] = o1[e] + bpv[4 + e];
        }
    }
}

// ---- fast main kernel: stage from pre-transposed bf16 x_t ----
__global__ __launch_bounds__(NT, 4)
void invol_mfma(const unsigned short* __restrict__ ws_all,
                const float* __restrict__ b_kg, const float* __restrict__ b_pw,
                float* __restrict__ out)
{
    __shared__ unsigned short xs[NPIX * XSTR];   // 25,920 B
    __shared__ float kvl[4 * 16 * 12];           //  3,072 B

    const int tile  = blockIdx.x;
    const int tileh = tile / 7;
    const int tilew = tile - tileh * 7;
    const int g = blockIdx.y;
    const int b = blockIdx.z;
    const int h0 = tileh * TH;
    const int w0 = tilew * TW;
    const int tid = threadIdx.x;

    // staging v4: 1296 x 16B tasks from x_t (channel-contiguous, coalesced runs)
    {
        const unsigned short* xti = ws_all + XT_OFF + (size_t)(b * GG + g) * HWSZ * 32;
        u32x4 vals[6];
        int lidx[6];
        #pragma unroll
        for (int k = 0; k < 6; ++k) {
            int t = tid + 256 * k;
            bool valid = (k < 5) || (t < 1296);
            int tc = valid ? t : 1295;
            int q = tc >> 2, kb2 = tc & 3;
            int r = (q * 57) >> 10;              // q/18 for q<324
            int col = q - 18 * r;
            int gh = h0 - 1 + r, gw = w0 - 1 + col;
            bool ok = valid && ((unsigned)gh < (unsigned)HH) && ((unsigned)gw < (unsigned)WW);
            int ghc = min(max(gh, 0), HH - 1);
            int gwc = min(max(gw, 0), WW - 1);
            u32x4 v = *(const u32x4*)(xti + ((size_t)(ghc * WW + gwc) * 32 + kb2 * 8));
            vals[k] = ok ? v : (u32x4){0, 0, 0, 0};
            lidx[k] = q * XSTR + kb2 * 8;
        }
        #pragma unroll
        for (int k = 0; k < 6; ++k) {
            int t = tid + 256 * k;
            if ((k < 5) || (t < 1296))
                *(short8*)&xs[lidx[k]] = __builtin_bit_cast(short8, vals[k]);
        }
    }
    __syncthreads();

    compute_tile(ws_all, b_kg, b_pw, out, xs, kvl, g, b, h0, w0, tid);
}

// ---- fallback main kernel (round-7 staging, fp32 x) for small ws ----
__global__ __launch_bounds__(NT, 4)
void invol_mfma_fb(const float* __restrict__ x,
                   const float* __restrict__ b_kg, const float* __restrict__ b_pw,
                   const unsigned short* __restrict__ ws, float* __restrict__ out)
{
    __shared__ unsigned short xs[NPIX * XSTR];
    __shared__ float kvl[4 * 16 * 12];

    const int tile  = blockIdx.x;
    const int tileh = tile / 7;
    const int tilew = tile - tileh * 7;
    const int g = blockIdx.y;
    const int b = blockIdx.z;
    const int h0 = tileh * TH;
    const int w0 = tilew * TW;
    const int tid = threadIdx.x;

    {
        const float* xg = x + (size_t)(b * CC + g * 32) * HWSZ;
        int c = 0, q = tid;
        #pragma unroll
        for (int batch = 0; batch < 3; ++batch) {
            const int bn = (batch == 2) ? 13 : 14;
            float v[14];
            int pki[14];
            #pragma unroll
            for (int it = 0; it < bn; ++it) {
                const int itg = batch * 14 + it;
                const bool valid = (itg < 40) || (tid < 128);
                int r   = (q * 57) >> 10;
                int col = q - 18 * r;
                int gh = h0 - 1 + r;
                int gw = w0 - 1 + col;
                bool ok = valid && ((unsigned)gh < (unsigned)HH) && ((unsigned)gw < (unsigned)WW);
                int ghc = min(max(gh, 0), HH - 1);
                int gwc = min(max(gw, 0), WW - 1);
                int cc  = min(c, 31);
                float t = xg[(size_t)cc * HWSZ + ghc * WW + gwc];
                v[it]   = ok ? t : 0.0f;
                pki[it] = q * XSTR + c;
                q += 256; if (q >= NPIX) { q -= NPIX; ++c; }
            }
            #pragma unroll
            for (int it = 0; it < bn; ++it)
                xs[pki[it]] = __builtin_bit_cast(unsigned short, __float2bfloat16(v[it]));
        }
    }
    __syncthreads();

    compute_tile(ws, b_kg, b_pw, out, xs, kvl, g, b, h0, w0, tid);
}

extern "C" void kernel_launch(void* const* d_in, const int* in_sizes, int n_in,
                              void* d_out, int out_size, void* d_ws, size_t ws_size,
                              hipStream_t stream)
{
    const float* x    = (const float*)d_in[0];
    const float* w_kg = (const float*)d_in[1];
    const float* b_kg = (const float*)d_in[2];
    const float* w_pw = (const float*)d_in[3];
    const float* b_pw = (const float*)d_in[4];
    float* out = (float*)d_out;
    unsigned short* ws = (unsigned short*)d_ws;

    int pre_blocks = (WK_ELEMS + WP_ELEMS + 255) / 256;
    hipLaunchKernelGGL(reorder_weights, dim3(pre_blocks), dim3(256), 0, stream,
                       w_kg, w_pw, ws);

    if (ws_size >= WS_NEED) {
        hipLaunchKernelGGL(transpose_x, dim3(28, GG, 8), dim3(256), 0, stream,
                           x, ws + XT_OFF);
        hipLaunchKernelGGL(invol_mfma, dim3(49, GG, 8), dim3(NT), 0, stream,
                           ws, b_kg, b_pw, out);
    } else {
        hipLaunchKernelGGL(invol_mfma_fb, dim3(49, GG, 8), dim3(NT), 0, stream,
                           x, b_kg, b_pw, ws, out);
    }
}

// Round 10
// 35.918 us; speedup vs baseline: 4.2453x; 1.1893x over previous
//
#include <hip/hip_runtime.h>
#include <hip/hip_bf16.h>

typedef __attribute__((ext_vector_type(8))) short short8;
typedef __attribute__((ext_vector_type(4))) float f32x4;
typedef __attribute__((ext_vector_type(4))) unsigned int u32x4;

#define GG 4
#define CC 128
#define HH 112
#define WW 112
#define HWSZ (HH * WW)
#define TH 16
#define TW 16
#define HALO 18
#define NPIX (HALO * HALO)      // 324
#define XSTR 40                 // bf16 per pixel row in LDS: pad 32->40 (80B; b128 reads conflict-free)
#define NT 256
#define WK_ELEMS (4 * 9 * 16 * 32)   // wk_reord[g][u][t16][c32], taps 9..15 zero
#define WP_ELEMS (4 * 2 * 16 * 32)   // wp_reord[g][mt][o16][c32]
#define W_TOTAL (WK_ELEMS + WP_ELEMS)
#define XT_OFF 32768                 // ushort offset of x_t in ws
#define XT_ELEMS (8 * 4 * HWSZ * 32)
#define WS_NEED ((size_t)(XT_OFF + XT_ELEMS) * 2)

__device__ __forceinline__ void reorder_one(int idx,
    const float* __restrict__ w_kg, const float* __restrict__ w_pw,
    unsigned short* __restrict__ ws)
{
    if (idx < WK_ELEMS) {
        int c = idx & 31, t = (idx >> 5) & 15, r = idx >> 9;
        int u = r % 9, g = r / 9;
        float v = (t < 9) ? w_kg[((g * 9 + t) * 32 + c) * 9 + u] : 0.0f;
        ws[idx] = __builtin_bit_cast(unsigned short, __float2bfloat16(v));
    } else if (idx < W_TOTAL) {
        int j = idx - WK_ELEMS;
        int c = j & 31, o = (j >> 5) & 15, mt = (j >> 9) & 1, g = j >> 10;
        float v = w_pw[(g * 32 + mt * 16 + o) * 32 + c];
        ws[idx] = __builtin_bit_cast(unsigned short, __float2bfloat16(v));
    }
}

// ---- standalone weight reorder (fallback path only) ----
__global__ __launch_bounds__(256)
void reorder_weights(const float* __restrict__ w_kg, const float* __restrict__ w_pw,
                     unsigned short* __restrict__ ws)
{
    reorder_one(blockIdx.x * 256 + threadIdx.x, w_kg, w_pw, ws);
}

// ---- transpose x -> x_t[b][g][pixel][c32] bf16; hc==28 blocks do weight reorder ----
__global__ __launch_bounds__(256, 4)
void transpose_x(const float* __restrict__ x,
                 const float* __restrict__ w_kg, const float* __restrict__ w_pw,
                 unsigned short* __restrict__ ws)
{
    __shared__ unsigned short xsT[32 * 452];     // [c][p448] pad 448->452; 28,928 B
    const int hc = blockIdx.x;                   // 0..27 transpose chunks; 28 = weights
    const int g = blockIdx.y, b = blockIdx.z;
    const int tid = threadIdx.x;

    if (hc == 28) {                              // 32 slices x 704 = 22,528 weight elems
        const int slice = b * GG + g;
        #pragma unroll
        for (int k = 0; k < 3; ++k) {
            int off = k * 256 + tid;
            if (off < 704)
                reorder_one(slice * 704 + off, w_kg, w_pw, ws);
        }
        return;
    }

    const float* xg = x + (size_t)(b * CC + g * 32) * HWSZ + hc * 4 * WW;
    unsigned short* xt = ws + XT_OFF;

    // phase 1: coalesced float4 reads (c-major, pixel-fastest), cvt, LDS write
    #pragma unroll
    for (int k = 0; k < 14; ++k) {               // 3584 tasks = 32c x 112 p4-groups
        int t = tid + 256 * k;
        int c = (t * 37450) >> 22;               // t/112, exact for t<3584
        int p4 = t - c * 112;
        float4 v = *(const float4*)(xg + (size_t)c * HWSZ + 4 * p4);
        int base = c * 452 + 4 * p4;
        xsT[base + 0] = __builtin_bit_cast(unsigned short, __float2bfloat16(v.x));
        xsT[base + 1] = __builtin_bit_cast(unsigned short, __float2bfloat16(v.y));
        xsT[base + 2] = __builtin_bit_cast(unsigned short, __float2bfloat16(v.z));
        xsT[base + 3] = __builtin_bit_cast(unsigned short, __float2bfloat16(v.w));
    }
    __syncthreads();

    // phase 2: gather 8 channels/pixel-chunk, write contiguous 16B (fully coalesced)
    unsigned short* xto = xt + ((size_t)(b * GG + g) * HWSZ + (size_t)hc * 448) * 32;
    #pragma unroll
    for (int k = 0; k < 7; ++k) {                // 1792 tasks = 448 px x 4 kb-chunks
        int t = tid + 256 * k;
        int p = t >> 2, kb = t & 3;
        unsigned r[4];
        #pragma unroll
        for (int j = 0; j < 4; ++j) {
            unsigned lo = xsT[(8 * kb + 2 * j) * 452 + p];
            unsigned hi = xsT[(8 * kb + 2 * j + 1) * 452 + p];
            r[j] = lo | (hi << 16);
        }
        *(u32x4*)(xto + (size_t)t * 8) = (u32x4){r[0], r[1], r[2], r[3]};
    }
}

// ---- per-thread weight fragments, loaded BEFORE staging (overlap global latency) ----
struct Frags {
    short8 afrag[9];
    short8 wpfrag[2];
    float bkv[4];
    float bpv[8];
};

__device__ __forceinline__ void load_frags(Frags& f,
    const unsigned short* __restrict__ wsw,
    const float* __restrict__ b_kg, const float* __restrict__ b_pw,
    int g, int tid)
{
    const int lane = tid & 63;
    const int px   = lane & 15;
    const int kb   = lane >> 4;

    #pragma unroll
    for (int u = 0; u < 9; ++u)
        f.afrag[u] = *(const short8*)(wsw + (((g * 9 + u) * 16 + px) * 32 + kb * 8));
    #pragma unroll
    for (int mt = 0; mt < 2; ++mt)
        f.wpfrag[mt] = *(const short8*)(wsw + WK_ELEMS + (((g * 2 + mt) * 16 + px) * 32 + kb * 8));

    const float* bk = b_kg + g * 9;
    const float* bp = b_pw + g * 32;
    #pragma unroll
    for (int e = 0; e < 4; ++e) {
        int t = 4 * kb + e;
        f.bkv[e] = bk[t < 9 ? t : 0];   // clamped; invalid taps never consumed
    }
    #pragma unroll
    for (int mt = 0; mt < 2; ++mt)
        #pragma unroll
        for (int e = 0; e < 4; ++e)
            f.bpv[mt * 4 + e] = bp[mt * 16 + 4 * kb + e];
}

// ---- shared compute body (proven kvl-roundtrip kv broadcast; NO ds_bpermute:
//      two independent failures (r5, r9, identical absmax 9.156) pin the
//      miscompute on the bpermute path despite formally-correct lane math) ----
__device__ __forceinline__ void compute_tile(const Frags& f,
    float* __restrict__ out, unsigned short* xs, float* kvl,
    int g, int b, int h0, int w0, int tid)
{
    const int lane = tid & 63;
    const int wid  = tid >> 6;
    const int px   = lane & 15;
    const int kb   = lane >> 4;

    float* kvp = &kvl[(wid * 16 + px) * 12];
    const size_t obase = ((size_t)(b * CC + g * 32) * HH + h0) * WW + w0 + px;

    #pragma unroll 1
    for (int r = 0; r < 4; ++r) {
        const int py = wid * 4 + r;

        short8 bfrag[9];
        #pragma unroll
        for (int u = 0; u < 9; ++u) {
            int q = (py + u / 3) * HALO + (px + u % 3);
            bfrag[u] = *(const short8*)&xs[q * XSTR + kb * 8];
        }

        // stage 1: kv = Wk * P; C/D: col=lane&15 (pixel), row=4*kb+e (tap)
        f32x4 kv = {0.f, 0.f, 0.f, 0.f};
        #pragma unroll
        for (int u = 0; u < 9; ++u)
            kv = __builtin_amdgcn_mfma_f32_16x16x32_bf16(f.afrag[u], bfrag[u], kv, 0, 0, 0);

        // kv cross-lane roundtrip (+bias): lane holds taps 4*kb..4*kb+3 of pixel px
        if (kb < 2) {
            f32x4 kvb;
            #pragma unroll
            for (int i = 0; i < 4; ++i) kvb[i] = kv[i] + f.bkv[i];
            *(f32x4*)&kvp[4 * kb] = kvb;
        } else if (kb == 2) {
            kvp[8] = kv[0] + f.bkv[0];
        }
        f32x4 k03 = *(const f32x4*)&kvp[0];
        f32x4 k47 = *(const f32x4*)&kvp[4];
        float k8 = kvp[8];
        float kvv[9] = {k03.x, k03.y, k03.z, k03.w, k47.x, k47.y, k47.z, k47.w, k8};

        // stage 2: involution on VALU, reusing bfrag registers
        float m[8] = {0.f, 0.f, 0.f, 0.f, 0.f, 0.f, 0.f, 0.f};
        #pragma unroll
        for (int u = 0; u < 9; ++u) {
            u32x4 bu = __builtin_bit_cast(u32x4, bfrag[u]);
            #pragma unroll
            for (int w = 0; w < 4; ++w) {
                unsigned d = bu[w];
                float lo = __builtin_bit_cast(float, d << 16);
                float hi = __builtin_bit_cast(float, d & 0xffff0000u);
                m[2 * w]     = fmaf(lo, kvv[u], m[2 * w]);
                m[2 * w + 1] = fmaf(hi, kvv[u], m[2 * w + 1]);
            }
        }

        // stage 3: pointwise via MFMA; m already in B-fragment order (k = 8kb+j)
        unsigned pk[4];
        #pragma unroll
        for (int w = 0; w < 4; ++w) {
            unsigned slo = __builtin_bit_cast(unsigned short, __float2bfloat16(m[2 * w]));
            unsigned shi = __builtin_bit_cast(unsigned short, __float2bfloat16(m[2 * w + 1]));
            pk[w] = slo | (shi << 16);
        }
        short8 mfrag = __builtin_bit_cast(short8, (u32x4){pk[0], pk[1], pk[2], pk[3]});

        f32x4 zero = {0.f, 0.f, 0.f, 0.f};
        f32x4 o0 = __builtin_amdgcn_mfma_f32_16x16x32_bf16(f.wpfrag[0], mfrag, zero, 0, 0, 0);
        f32x4 o1 = __builtin_amdgcn_mfma_f32_16x16x32_bf16(f.wpfrag[1], mfrag, zero, 0, 0, 0);

        #pragma unroll
        for (int e = 0; e < 4; ++e) {
            int o = 4 * kb + e;
            out[obase + (size_t)o * HWSZ + (size_t)py * WW] = o0[e] + f.bpv[e];
            out[obase + (size_t)(o + 16) * HWSZ + (size_t)py * WW] = o1[e] + f.bpv[4 + e];
        }
    }
}

// ---- fast main kernel: stage from pre-transposed bf16 x_t ----
__global__ __launch_bounds__(NT, 4)
void invol_mfma(const unsigned short* __restrict__ ws_all,
                const float* __restrict__ b_kg, const float* __restrict__ b_pw,
                float* __restrict__ out)
{
    __shared__ unsigned short xs[NPIX * XSTR];   // 25,920 B
    __shared__ float kvl[4 * 16 * 12];           //  3,072 B

    const int tile  = blockIdx.x;
    const int tileh = tile / 7;
    const int tilew = tile - tileh * 7;
    const int g = blockIdx.y;
    const int b = blockIdx.z;
    const int h0 = tileh * TH;
    const int w0 = tilew * TW;
    const int tid = threadIdx.x;

    // weight fragments first: global latency overlaps the staging phase below
    Frags f;
    load_frags(f, ws_all, b_kg, b_pw, g, tid);

    // staging v4: 1296 x 16B tasks from x_t (channel-contiguous, coalesced runs)
    {
        const unsigned short* xti = ws_all + XT_OFF + (size_t)(b * GG + g) * HWSZ * 32;
        u32x4 vals[6];
        int lidx[6];
        #pragma unroll
        for (int k = 0; k < 6; ++k) {
            int t = tid + 256 * k;
            bool valid = (k < 5) || (t < 1296);
            int tc = valid ? t : 1295;
            int q = tc >> 2, kb2 = tc & 3;
            int r = (q * 57) >> 10;              // q/18 for q<324
            int col = q - 18 * r;
            int gh = h0 - 1 + r, gw = w0 - 1 + col;
            bool ok = valid && ((unsigned)gh < (unsigned)HH) && ((unsigned)gw < (unsigned)WW);
            int ghc = min(max(gh, 0), HH - 1);
            int gwc = min(max(gw, 0), WW - 1);
            u32x4 v = *(const u32x4*)(xti + ((size_t)(ghc * WW + gwc) * 32 + kb2 * 8));
            vals[k] = ok ? v : (u32x4){0, 0, 0, 0};
            lidx[k] = q * XSTR + kb2 * 8;
        }
        #pragma unroll
        for (int k = 0; k < 6; ++k) {
            int t = tid + 256 * k;
            if ((k < 5) || (t < 1296))
                *(short8*)&xs[lidx[k]] = __builtin_bit_cast(short8, vals[k]);
        }
    }
    __syncthreads();

    compute_tile(f, out, xs, kvl, g, b, h0, w0, tid);
}

// ---- fallback main kernel (direct fp32 staging) for small ws ----
__global__ __launch_bounds__(NT, 4)
void invol_mfma_fb(const float* __restrict__ x,
                   const float* __restrict__ b_kg, const float* __restrict__ b_pw,
                   const unsigned short* __restrict__ ws, float* __restrict__ out)
{
    __shared__ unsigned short xs[NPIX * XSTR];
    __shared__ float kvl[4 * 16 * 12];

    const int tile  = blockIdx.x;
    const int tileh = tile / 7;
    const int tilew = tile - tileh * 7;
    const int g = blockIdx.y;
    const int b = blockIdx.z;
    const int h0 = tileh * TH;
    const int w0 = tilew * TW;
    const int tid = threadIdx.x;

    Frags f;
    load_frags(f, ws, b_kg, b_pw, g, tid);

    {
        const float* xg = x + (size_t)(b * CC + g * 32) * HWSZ;
        int c = 0, q = tid;
        #pragma unroll
        for (int batch = 0; batch < 3; ++batch) {
            const int bn = (batch == 2) ? 13 : 14;
            float v[14];
            int pki[14];
            #pragma unroll
            for (int it = 0; it < bn; ++it) {
                const int itg = batch * 14 + it;
                const bool valid = (itg < 40) || (tid < 128);
                int r   = (q * 57) >> 10;
                int col = q - 18 * r;
                int gh = h0 - 1 + r;
                int gw = w0 - 1 + col;
                bool ok = valid && ((unsigned)gh < (unsigned)HH) && ((unsigned)gw < (unsigned)WW);
                int ghc = min(max(gh, 0), HH - 1);
                int gwc = min(max(gw, 0), WW - 1);
                int cc  = min(c, 31);
                float t = xg[(size_t)cc * HWSZ + ghc * WW + gwc];
                v[it]   = ok ? t : 0.0f;
                pki[it] = q * XSTR + c;
                q += 256; if (q >= NPIX) { q -= NPIX; ++c; }
            }
            #pragma unroll
            for (int it = 0; it < bn; ++it)
                xs[pki[it]] = __builtin_bit_cast(unsigned short, __float2bfloat16(v[it]));
        }
    }
    __syncthreads();

    compute_tile(f, out, xs, kvl, g, b, h0, w0, tid);
}

extern "C" void kernel_launch(void* const* d_in, const int* in_sizes, int n_in,
                              void* d_out, int out_size, void* d_ws, size_t ws_size,
                              hipStream_t stream)
{
    const float* x    = (const float*)d_in[0];
    const float* w_kg = (const float*)d_in[1];
    const float* b_kg = (const float*)d_in[2];
    const float* w_pw = (const float*)d_in[3];
    const float* b_pw = (const float*)d_in[4];
    float* out = (float*)d_out;
    unsigned short* ws = (unsigned short*)d_ws;

    if (ws_size >= WS_NEED) {
        hipLaunchKernelGGL(transpose_x, dim3(29, GG, 8), dim3(256), 0, stream,
                           x, w_kg, w_pw, ws);
        hipLaunchKernelGGL(invol_mfma, dim3(49, GG, 8), dim3(NT), 0, stream,
                           ws, b_kg, b_pw, out);
    } else {
        int pre_blocks = (W_TOTAL + 255) / 256;
        hipLaunchKernelGGL(reorder_weights, dim3(pre_blocks), dim3(256), 0, stream,
                           w_kg, w_pw, ws);
        hipLaunchKernelGGL(invol_mfma_fb, dim3(49, GG, 8), dim3(NT), 0, stream,
                           x, b_kg, b_pw, ws, out);
    }
}